// Round 1
// baseline (366.514 us; speedup 1.0000x reference)
//
#include <hip/hip_runtime.h>
#include <math.h>

// Problem constants
#define D0 32
#define D1 256
#define D2 256
#define HS2 129            // rfft half-spectrum last dim
#define NVOX (D0*D1*D2)    // 2097152
#define KMAX 4
#define NK 9               // k in [-4,4]
#define NK2 5              // k2 in [0,4]
#define NCH 3
#define BATCH 4
#define FCH 3
// C layout: [ch][i0][i1][i2][2]  (i0=k0+4, i1=k1+4, i2=k2)
#define C_FLOATS (NCH*NK*NK*NK2*2)   // 2430
// S layout: [(ch*5+k2)*2 + reim][8192]
#define S_FLOATS (NCH*NK2*2*8192)    // 245760

__global__ __launch_bounds__(256) void build_C(
    const float* __restrict__ seeds, const float* __restrict__ Pk,
    const float* __restrict__ defscale, const int* __restrict__ feed_idx,
    int fdim, float* __restrict__ C, int* __restrict__ fed)
{
    int t = threadIdx.x;
    for (int i = t; i < C_FLOATS; i += 256) C[i] = 0.0f;
    for (int i = t; i < NK*NK; i += 256) fed[i] = 0;
    __syncthreads();
    float ds0 = defscale[0], ds1 = defscale[1], ds2 = defscale[2];
    const int STR_RI = D0 * D1 * HS2;   // 1056768
    const int STR_A  = D1 * HS2;        // 33024
    for (int j = t; j < fdim; j += 256) {
        int idx = feed_idx[j];
        int ri = idx / STR_RI; int r = idx - ri * STR_RI;
        int a  = r / STR_A;    r -= a * STR_A;
        int b  = r / HS2;      int c = r - b * HS2;
        int k0 = (a < D0/2) ? a : a - D0;
        int k1 = (b < D1/2) ? b : b - D1;
        if (k0 < -KMAX || k0 > KMAX || k1 < -KMAX || k1 > KMAX || c > KMAX) continue;
        int i0 = k0 + KMAX, i1 = k1 + KMAX;
        float pk = Pk[j];
        float v0 = seeds[0*fdim + j] * pk * ds0;
        float v1 = seeds[1*fdim + j] * pk * ds1;
        float v2 = seeds[2*fdim + j] * pk * ds2;
        int base = (((0*NK + i0)*NK + i1)*NK2 + c)*2 + ri;
        C[base]                 = v0;
        C[base + 1*NK*NK*NK2*2] = v1;
        C[base + 2*NK*NK*NK2*2] = v2;
        if (c == 0) fed[i0*NK + i1] = 1;
    }
    __syncthreads();
    // hermitian completion on the k2=0 plane: unfed <- conj(mirror)
    for (int tt = t; tt < NK*NK; tt += 256) {
        if (!fed[tt]) {
            int i0 = tt / NK, i1 = tt - i0*NK;
            int m0 = (NK-1) - i0, m1 = (NK-1) - i1;
            for (int ch = 0; ch < NCH; ++ch) {
                int dst = (((ch*NK + i0)*NK + i1)*NK2 + 0)*2;
                int src = (((ch*NK + m0)*NK + m1)*NK2 + 0)*2;
                float sr = C[src], si = C[src+1];
                C[dst]   = sr;
                C[dst+1] = -si;
            }
        }
    }
}

__global__ __launch_bounds__(256) void build_S(
    const float* __restrict__ C, float* __restrict__ S)
{
    int zy = blockIdx.x * 256 + threadIdx.x;   // 32 blocks * 256 = 8192
    int z = zy >> 8, y = zy & 255;

    // twiddle tables W0(k0,z), W1(k1,y), index i = k+4
    float w0r[NK], w0i[NK], w1r[NK], w1i[NK];
    {
        float th = (float)z * (6.28318530717958647692f / (float)D0);
        float sb, cb; sincosf(th, &sb, &cb);
        w0r[KMAX] = 1.0f; w0i[KMAX] = 0.0f;
        float pr = 1.0f, pi = 0.0f;
        for (int k = 1; k <= KMAX; ++k) {
            float nr = pr*cb - pi*sb, ni = pr*sb + pi*cb;
            pr = nr; pi = ni;
            w0r[KMAX+k] = pr; w0i[KMAX+k] = pi;
            w0r[KMAX-k] = pr; w0i[KMAX-k] = -pi;
        }
    }
    {
        float th = (float)y * (6.28318530717958647692f / (float)D1);
        float sb, cb; sincosf(th, &sb, &cb);
        w1r[KMAX] = 1.0f; w1i[KMAX] = 0.0f;
        float pr = 1.0f, pi = 0.0f;
        for (int k = 1; k <= KMAX; ++k) {
            float nr = pr*cb - pi*sb, ni = pr*sb + pi*cb;
            pr = nr; pi = ni;
            w1r[KMAX+k] = pr; w1i[KMAX+k] = pi;
            w1r[KMAX-k] = pr; w1i[KMAX-k] = -pi;
        }
    }

    float Sr[NCH*NK2], Si[NCH*NK2];
    #pragma unroll
    for (int i = 0; i < NCH*NK2; ++i) { Sr[i] = 0.0f; Si[i] = 0.0f; }

    for (int i0 = 0; i0 < NK; ++i0) {
        for (int i1 = 0; i1 < NK; ++i1) {
            float Tr = w0r[i0]*w1r[i1] - w0i[i0]*w1i[i1];
            float Ti = w0r[i0]*w1i[i1] + w0i[i0]*w1r[i1];
            const float* Cp = C + (i0*NK + i1)*NK2*2;
            #pragma unroll
            for (int ch = 0; ch < NCH; ++ch) {
                #pragma unroll
                for (int k2 = 0; k2 < NK2; ++k2) {
                    float cr = Cp[ch*(NK*NK*NK2*2) + k2*2];
                    float ci = Cp[ch*(NK*NK*NK2*2) + k2*2 + 1];
                    int o = ch*NK2 + k2;
                    Sr[o] += cr*Tr - ci*Ti;
                    Si[o] += cr*Ti + ci*Tr;
                }
            }
        }
    }

    const float invN = 1.0f / (float)NVOX;
    #pragma unroll
    for (int ch = 0; ch < NCH; ++ch) {
        #pragma unroll
        for (int k2 = 0; k2 < NK2; ++k2) {
            int o = ch*NK2 + k2;
            float sc = (k2 == 0) ? invN : 2.0f*invN;
            S[(o*2 + 0)*8192 + zy] = Sr[o] * sc;
            S[(o*2 + 1)*8192 + zy] = Si[o] * sc;
        }
    }
}

__global__ __launch_bounds__(256) void deform_sample(
    const float* __restrict__ fr, const float* __restrict__ S,
    float* __restrict__ out)
{
    int zy = blockIdx.x;             // 8192 blocks
    int z = zy >> 8, y = zy & 255;
    int x = threadIdx.x;

    // block-uniform S loads (k2=0 imag is ~0 and mathematically zero -> skip)
    float s0r[NCH], skr[NCH][KMAX], ski[NCH][KMAX];
    #pragma unroll
    for (int ch = 0; ch < NCH; ++ch) {
        s0r[ch] = S[((ch*NK2 + 0)*2 + 0)*8192 + zy];
        #pragma unroll
        for (int k = 1; k <= KMAX; ++k) {
            skr[ch][k-1] = S[((ch*NK2 + k)*2 + 0)*8192 + zy];
            ski[ch][k-1] = S[((ch*NK2 + k)*2 + 1)*8192 + zy];
        }
    }

    // cos/sin(k*theta) for k=1..4, theta = 2*pi*x/256
    float th = (float)x * (6.28318530717958647692f / (float)D2);
    float sb, cb; sincosf(th, &sb, &cb);
    float ckr[KMAX], cks[KMAX];
    ckr[0] = cb; cks[0] = sb;
    #pragma unroll
    for (int k = 1; k < KMAX; ++k) {
        float nr = ckr[k-1]*cb - cks[k-1]*sb;
        float ni = cks[k-1]*cb + ckr[k-1]*sb;
        ckr[k] = nr; cks[k] = ni;
    }

    float d[NCH];
    #pragma unroll
    for (int ch = 0; ch < NCH; ++ch) {
        float acc = s0r[ch];
        #pragma unroll
        for (int k = 0; k < KMAX; ++k)
            acc += skr[ch][k]*ckr[k] - ski[ch][k]*cks[k];
        d[ch] = acc;
    }

    // coordinates collapse to: f = clip(coord - disp, 0, dim-1)
    float fz = fminf(fmaxf((float)z - d[0], 0.0f), (float)(D0-1));
    float fy = fminf(fmaxf((float)y - d[1], 0.0f), (float)(D1-1));
    float fx = fminf(fmaxf((float)x - d[2], 0.0f), (float)(D2-1));

    float z0f = floorf(fz), y0f = floorf(fy), x0f = floorf(fx);
    int z0 = (int)z0f, y0 = (int)y0f, x0 = (int)x0f;
    int z1 = min(z0 + 1, D0-1), y1 = min(y0 + 1, D1-1), x1 = min(x0 + 1, D2-1);
    float wz = fz - z0f, wy = fy - y0f, wx = fx - x0f;
    float wz0 = 1.0f - wz, wy0 = 1.0f - wy, wx0 = 1.0f - wx;

    int o00 = (z0 << 16) + (y0 << 8);
    int o01 = (z0 << 16) + (y1 << 8);
    int o10 = (z1 << 16) + (y0 << 8);
    int o11 = (z1 << 16) + (y1 << 8);
    int obase = (z << 16) + (y << 8) + x;

    #pragma unroll
    for (int bc = 0; bc < BATCH*FCH; ++bc) {
        const float* __restrict__ v = fr + ((size_t)bc << 21);
        float c00 = v[o00 + x0]*wx0 + v[o00 + x1]*wx;
        float c01 = v[o01 + x0]*wx0 + v[o01 + x1]*wx;
        float c10 = v[o10 + x0]*wx0 + v[o10 + x1]*wx;
        float c11 = v[o11 + x0]*wx0 + v[o11 + x1]*wx;
        float c0 = c00*wy0 + c01*wy;
        float c1 = c10*wy0 + c11*wy;
        out[((size_t)bc << 21) + obase] = c0*wz0 + c1*wz;
    }
}

extern "C" void kernel_launch(void* const* d_in, const int* in_sizes, int n_in,
                              void* d_out, int out_size, void* d_ws, size_t ws_size,
                              hipStream_t stream) {
    const float* fr       = (const float*)d_in[0];
    const float* seeds    = (const float*)d_in[1];
    const float* Pk       = (const float*)d_in[2];
    const float* defscale = (const float*)d_in[3];
    // d_in[4] = grid (values are exactly meshgrid(arange) -> recomputed in-kernel)
    const int*   feed_idx = (const int*)d_in[5];
    int fdim = in_sizes[2];

    float* ws = (float*)d_ws;
    float* C   = ws;                       // 2430 floats
    int*   fed = (int*)(ws + 2432);        // 81 ints
    float* S   = ws + 4096;                // 245760 floats (~0.96 MB total)

    build_C<<<1, 256, 0, stream>>>(seeds, Pk, defscale, feed_idx, fdim, C, fed);
    build_S<<<32, 256, 0, stream>>>(C, S);
    deform_sample<<<8192, 256, 0, stream>>>(fr, S, (float*)d_out);
}

// Round 2
// 334.644 us; speedup vs baseline: 1.0952x; 1.0952x over previous
//
#include <hip/hip_runtime.h>
#include <math.h>

// Problem constants
#define D0 32
#define D1 256
#define D2 256
#define HS2 129            // rfft half-spectrum last dim
#define NVOX (D0*D1*D2)    // 2097152
#define KMAX 4
#define NK 9               // k in [-4,4]
#define NK2 5              // k2 in [0,4]
#define NCH 3
#define BATCH 4
#define FCH 3
// C layout: [ch][i0][i1][i2][2]  (i0=k0+4, i1=k1+4, i2=k2)
#define C_FLOATS (NCH*NK*NK*NK2*2)   // 2430
// S layout: [(ch*5+k2)*2 + reim][8192]
#define S_FLOATS (NCH*NK2*2*8192)    // 245760

// Fused: each of the 32 blocks redundantly builds the dense coefficient cube C
// in LDS (cost is trivial: ~fdim scattered loads), then computes S for its 256
// (z,y) pairs. Removes the build_C launch + dependency.
__global__ __launch_bounds__(256) void build_S_fused(
    const float* __restrict__ seeds, const float* __restrict__ Pk,
    const float* __restrict__ defscale, const int* __restrict__ feed_idx,
    int fdim, float* __restrict__ S)
{
    __shared__ float C[C_FLOATS];
    __shared__ int fed[NK*NK];
    int t = threadIdx.x;
    for (int i = t; i < C_FLOATS; i += 256) C[i] = 0.0f;
    for (int i = t; i < NK*NK; i += 256) fed[i] = 0;
    __syncthreads();
    float ds0 = defscale[0], ds1 = defscale[1], ds2 = defscale[2];
    const int STR_RI = D0 * D1 * HS2;   // 1056768
    const int STR_A  = D1 * HS2;        // 33024
    for (int j = t; j < fdim; j += 256) {
        int idx = feed_idx[j];
        int ri = idx / STR_RI; int r = idx - ri * STR_RI;
        int a  = r / STR_A;    r -= a * STR_A;
        int b  = r / HS2;      int c = r - b * HS2;
        int k0 = (a < D0/2) ? a : a - D0;
        int k1 = (b < D1/2) ? b : b - D1;
        if (k0 < -KMAX || k0 > KMAX || k1 < -KMAX || k1 > KMAX || c > KMAX) continue;
        int i0 = k0 + KMAX, i1 = k1 + KMAX;
        float pk = Pk[j];
        float v0 = seeds[0*fdim + j] * pk * ds0;
        float v1 = seeds[1*fdim + j] * pk * ds1;
        float v2 = seeds[2*fdim + j] * pk * ds2;
        int base = ((i0*NK + i1)*NK2 + c)*2 + ri;
        C[base]                 = v0;
        C[base + 1*NK*NK*NK2*2] = v1;
        C[base + 2*NK*NK*NK2*2] = v2;
        if (c == 0) fed[i0*NK + i1] = 1;
    }
    __syncthreads();
    // hermitian completion on the k2=0 plane: unfed <- conj(mirror)
    if (t < NK*NK) {
        if (!fed[t]) {
            int i0 = t / NK, i1 = t - i0*NK;
            int m0 = (NK-1) - i0, m1 = (NK-1) - i1;
            for (int ch = 0; ch < NCH; ++ch) {
                int dst = ((ch*NK*NK + i0*NK + i1)*NK2 + 0)*2;
                int src = ((ch*NK*NK + m0*NK + m1)*NK2 + 0)*2;
                float sr = C[src], si = C[src+1];
                C[dst]   = sr;
                C[dst+1] = -si;
            }
        }
    }
    __syncthreads();

    int zy = blockIdx.x * 256 + t;   // 32 blocks * 256 = 8192
    int z = zy >> 8, y = zy & 255;

    // twiddle tables W0(k0,z), W1(k1,y), index i = k+4
    float w0r[NK], w0i[NK], w1r[NK], w1i[NK];
    {
        float th = (float)z * (6.28318530717958647692f / (float)D0);
        float sb, cb; sincosf(th, &sb, &cb);
        w0r[KMAX] = 1.0f; w0i[KMAX] = 0.0f;
        float pr = 1.0f, pi = 0.0f;
        for (int k = 1; k <= KMAX; ++k) {
            float nr = pr*cb - pi*sb, ni = pr*sb + pi*cb;
            pr = nr; pi = ni;
            w0r[KMAX+k] = pr; w0i[KMAX+k] = pi;
            w0r[KMAX-k] = pr; w0i[KMAX-k] = -pi;
        }
    }
    {
        float th = (float)y * (6.28318530717958647692f / (float)D1);
        float sb, cb; sincosf(th, &sb, &cb);
        w1r[KMAX] = 1.0f; w1i[KMAX] = 0.0f;
        float pr = 1.0f, pi = 0.0f;
        for (int k = 1; k <= KMAX; ++k) {
            float nr = pr*cb - pi*sb, ni = pr*sb + pi*cb;
            pr = nr; pi = ni;
            w1r[KMAX+k] = pr; w1i[KMAX+k] = pi;
            w1r[KMAX-k] = pr; w1i[KMAX-k] = -pi;
        }
    }

    float Sr[NCH*NK2], Si[NCH*NK2];
    #pragma unroll
    for (int i = 0; i < NCH*NK2; ++i) { Sr[i] = 0.0f; Si[i] = 0.0f; }

    for (int i0 = 0; i0 < NK; ++i0) {
        for (int i1 = 0; i1 < NK; ++i1) {
            float Tr = w0r[i0]*w1r[i1] - w0i[i0]*w1i[i1];
            float Ti = w0r[i0]*w1i[i1] + w0i[i0]*w1r[i1];
            const float* Cp = C + (i0*NK + i1)*NK2*2;
            #pragma unroll
            for (int ch = 0; ch < NCH; ++ch) {
                #pragma unroll
                for (int k2 = 0; k2 < NK2; ++k2) {
                    float cr = Cp[ch*(NK*NK*NK2*2) + k2*2];
                    float ci = Cp[ch*(NK*NK*NK2*2) + k2*2 + 1];
                    int o = ch*NK2 + k2;
                    Sr[o] += cr*Tr - ci*Ti;
                    Si[o] += cr*Ti + ci*Tr;
                }
            }
        }
    }

    const float invN = 1.0f / (float)NVOX;
    #pragma unroll
    for (int ch = 0; ch < NCH; ++ch) {
        #pragma unroll
        for (int k2 = 0; k2 < NK2; ++k2) {
            int o = ch*NK2 + k2;
            float sc = (k2 == 0) ? invN : 2.0f*invN;
            S[(o*2 + 0)*8192 + zy] = Sr[o] * sc;
            S[(o*2 + 1)*8192 + zy] = Si[o] * sc;
        }
    }
}

__global__ __launch_bounds__(256) void deform_sample(
    const float* __restrict__ fr, const float* __restrict__ S,
    float* __restrict__ out)
{
    // XCD-aware swizzle: dispatch round-robins blocks over 8 XCDs (block i ->
    // XCD i&7, per-XCD L2s non-coherent). Map so each XCD owns a CONTIGUOUS
    // 1024-row zy slab: neighbor output rows (which gather nearly identical
    // input rows) then share one L2.  FETCH was 5.4x ideal without this.
    int zy = ((blockIdx.x & 7) << 10) + (blockIdx.x >> 3);
    int z = zy >> 8, y = zy & 255;
    int x = threadIdx.x;

    // block-uniform S loads (k2=0 imag is mathematically zero -> skip)
    float s0r[NCH], skr[NCH][KMAX], ski[NCH][KMAX];
    #pragma unroll
    for (int ch = 0; ch < NCH; ++ch) {
        s0r[ch] = S[((ch*NK2 + 0)*2 + 0)*8192 + zy];
        #pragma unroll
        for (int k = 1; k <= KMAX; ++k) {
            skr[ch][k-1] = S[((ch*NK2 + k)*2 + 0)*8192 + zy];
            ski[ch][k-1] = S[((ch*NK2 + k)*2 + 1)*8192 + zy];
        }
    }

    // cos/sin(k*theta) for k=1..4, theta = 2*pi*x/256
    float th = (float)x * (6.28318530717958647692f / (float)D2);
    float sb, cb; sincosf(th, &sb, &cb);
    float ckr[KMAX], cks[KMAX];
    ckr[0] = cb; cks[0] = sb;
    #pragma unroll
    for (int k = 1; k < KMAX; ++k) {
        float nr = ckr[k-1]*cb - cks[k-1]*sb;
        float ni = cks[k-1]*cb + ckr[k-1]*sb;
        ckr[k] = nr; cks[k] = ni;
    }

    float d[NCH];
    #pragma unroll
    for (int ch = 0; ch < NCH; ++ch) {
        float acc = s0r[ch];
        #pragma unroll
        for (int k = 0; k < KMAX; ++k)
            acc += skr[ch][k]*ckr[k] - ski[ch][k]*cks[k];
        d[ch] = acc;
    }

    // coordinates collapse to: f = clip(coord - disp, 0, dim-1)
    float fz = fminf(fmaxf((float)z - d[0], 0.0f), (float)(D0-1));
    float fy = fminf(fmaxf((float)y - d[1], 0.0f), (float)(D1-1));
    float fx = fminf(fmaxf((float)x - d[2], 0.0f), (float)(D2-1));

    float z0f = floorf(fz), y0f = floorf(fy), x0f = floorf(fx);
    int z0 = (int)z0f, y0 = (int)y0f, x0 = (int)x0f;
    int z1 = min(z0 + 1, D0-1), y1 = min(y0 + 1, D1-1), x1 = min(x0 + 1, D2-1);
    float wz = fz - z0f, wy = fy - y0f, wx = fx - x0f;
    float wz0 = 1.0f - wz, wy0 = 1.0f - wy, wx0 = 1.0f - wx;

    int o00 = (z0 << 16) + (y0 << 8);
    int o01 = (z0 << 16) + (y1 << 8);
    int o10 = (z1 << 16) + (y0 << 8);
    int o11 = (z1 << 16) + (y1 << 8);
    int obase = (z << 16) + (y << 8) + x;

    #pragma unroll
    for (int bc = 0; bc < BATCH*FCH; ++bc) {
        const float* __restrict__ v = fr + ((size_t)bc << 21);
        float c00 = v[o00 + x0]*wx0 + v[o00 + x1]*wx;
        float c01 = v[o01 + x0]*wx0 + v[o01 + x1]*wx;
        float c10 = v[o10 + x0]*wx0 + v[o10 + x1]*wx;
        float c11 = v[o11 + x0]*wx0 + v[o11 + x1]*wx;
        float c0 = c00*wy0 + c01*wy;
        float c1 = c10*wy0 + c11*wy;
        // streaming store: don't let 98 MB of output evict fr rows from L2
        __builtin_nontemporal_store(c0*wz0 + c1*wz, &out[((size_t)bc << 21) + obase]);
    }
}

extern "C" void kernel_launch(void* const* d_in, const int* in_sizes, int n_in,
                              void* d_out, int out_size, void* d_ws, size_t ws_size,
                              hipStream_t stream) {
    const float* fr       = (const float*)d_in[0];
    const float* seeds    = (const float*)d_in[1];
    const float* Pk       = (const float*)d_in[2];
    const float* defscale = (const float*)d_in[3];
    // d_in[4] = grid (values are exactly meshgrid(arange) -> recomputed in-kernel)
    const int*   feed_idx = (const int*)d_in[5];
    int fdim = in_sizes[2];

    float* S = (float*)d_ws;   // 245760 floats (~0.96 MB)

    build_S_fused<<<32, 256, 0, stream>>>(seeds, Pk, defscale, feed_idx, fdim, S);
    deform_sample<<<8192, 256, 0, stream>>>(fr, S, (float*)d_out);
}

// Round 3
// 324.797 us; speedup vs baseline: 1.1284x; 1.0303x over previous
//
#include <hip/hip_runtime.h>
#include <math.h>

// Problem constants
#define D0 32
#define D1 256
#define D2 256
#define HS2 129            // rfft half-spectrum last dim
#define NVOX (D0*D1*D2)    // 2097152
#define KMAX 4
#define NK 9               // k in [-4,4]
#define NK2 5              // k2 in [0,4]
#define NCH 3
#define BATCH 4
#define FCH 3
#define NBC (BATCH*FCH)    // 12
// C layout: [ch][i0][i1][i2][2]  (i0=k0+4, i1=k1+4, i2=k2)
#define C_FLOATS (NCH*NK*NK*NK2*2)   // 2430
// S layout: [(ch*5+k2)*2 + reim][8192]

// 256 blocks x 256 threads. Each block: build dense C cube in LDS (scatter,
// ~fdim loads — trivial), then 32 zy rows per block with the 81-mode sum
// split 8 ways across consecutive lanes, reduced via width-8 shuffles.
// Old version used 32 blocks (32 CUs, 1 wave/SIMD, exposed LDS latency) and
// was nearly as slow as the main kernel.
__global__ __launch_bounds__(256) void build_S(
    const float* __restrict__ seeds, const float* __restrict__ Pk,
    const float* __restrict__ defscale, const int* __restrict__ feed_idx,
    int fdim, float* __restrict__ S)
{
    __shared__ float C[C_FLOATS];
    __shared__ int fed[NK*NK];
    int t = threadIdx.x;
    for (int i = t; i < C_FLOATS; i += 256) C[i] = 0.0f;
    if (t < NK*NK) fed[t] = 0;
    __syncthreads();
    float ds0 = defscale[0], ds1 = defscale[1], ds2 = defscale[2];
    const int STR_RI = D0 * D1 * HS2;   // 1056768
    const int STR_A  = D1 * HS2;        // 33024
    for (int j = t; j < fdim; j += 256) {
        int idx = feed_idx[j];
        int ri = idx / STR_RI; int r = idx - ri * STR_RI;
        int a  = r / STR_A;    r -= a * STR_A;
        int b  = r / HS2;      int c = r - b * HS2;
        int k0 = (a < D0/2) ? a : a - D0;
        int k1 = (b < D1/2) ? b : b - D1;
        if (k0 < -KMAX || k0 > KMAX || k1 < -KMAX || k1 > KMAX || c > KMAX) continue;
        int i0 = k0 + KMAX, i1 = k1 + KMAX;
        float pk = Pk[j];
        int base = ((i0*NK + i1)*NK2 + c)*2 + ri;
        C[base]                 = seeds[0*fdim + j] * pk * ds0;
        C[base + 1*NK*NK*NK2*2] = seeds[1*fdim + j] * pk * ds1;
        C[base + 2*NK*NK*NK2*2] = seeds[2*fdim + j] * pk * ds2;
        if (c == 0) fed[i0*NK + i1] = 1;
    }
    __syncthreads();
    // hermitian completion on the k2=0 plane: unfed <- conj(mirror)
    if (t < NK*NK && !fed[t]) {
        int i0 = t / NK, i1 = t - i0*NK;
        int m0 = (NK-1) - i0, m1 = (NK-1) - i1;
        for (int ch = 0; ch < NCH; ++ch) {
            int dst = ((ch*NK*NK + i0*NK + i1)*NK2 + 0)*2;
            int src = ((ch*NK*NK + m0*NK + m1)*NK2 + 0)*2;
            C[dst]   = C[src];
            C[dst+1] = -C[src+1];
        }
    }
    __syncthreads();

    int zyl = t >> 3;           // 0..31  (consecutive lanes share zyl)
    int g   = t & 7;            // mode group 0..7
    int zy = blockIdx.x * 32 + zyl;
    int z = zy >> 8, y = zy & 255;

    // twiddle tables W0(k0,z), W1(k1,y), index i = k+4
    float w0r[NK], w0i[NK], w1r[NK], w1i[NK];
    {
        float th = (float)z * (6.28318530717958647692f / (float)D0);
        float sb, cb; __sincosf(th, &sb, &cb);
        w0r[KMAX] = 1.0f; w0i[KMAX] = 0.0f;
        float pr = 1.0f, pi = 0.0f;
        #pragma unroll
        for (int k = 1; k <= KMAX; ++k) {
            float nr = pr*cb - pi*sb, ni = pr*sb + pi*cb;
            pr = nr; pi = ni;
            w0r[KMAX+k] = pr; w0i[KMAX+k] = pi;
            w0r[KMAX-k] = pr; w0i[KMAX-k] = -pi;
        }
    }
    {
        float th = (float)y * (6.28318530717958647692f / (float)D1);
        float sb, cb; __sincosf(th, &sb, &cb);
        w1r[KMAX] = 1.0f; w1i[KMAX] = 0.0f;
        float pr = 1.0f, pi = 0.0f;
        #pragma unroll
        for (int k = 1; k <= KMAX; ++k) {
            float nr = pr*cb - pi*sb, ni = pr*sb + pi*cb;
            pr = nr; pi = ni;
            w1r[KMAX+k] = pr; w1i[KMAX+k] = pi;
            w1r[KMAX-k] = pr; w1i[KMAX-k] = -pi;
        }
    }

    float Sr[NCH*NK2], Si[NCH*NK2];
    #pragma unroll
    for (int i = 0; i < NCH*NK2; ++i) { Sr[i] = 0.0f; Si[i] = 0.0f; }

    for (int m = g; m < NK*NK; m += 8) {
        int i0 = m / NK, i1 = m - i0*NK;
        float Tr = w0r[i0]*w1r[i1] - w0i[i0]*w1i[i1];
        float Ti = w0r[i0]*w1i[i1] + w0i[i0]*w1r[i1];
        const float* Cp = C + m*NK2*2;
        #pragma unroll
        for (int ch = 0; ch < NCH; ++ch) {
            #pragma unroll
            for (int k2 = 0; k2 < NK2; ++k2) {
                float cr = Cp[ch*(NK*NK*NK2*2) + k2*2];
                float ci = Cp[ch*(NK*NK*NK2*2) + k2*2 + 1];
                int o = ch*NK2 + k2;
                Sr[o] += cr*Tr - ci*Ti;
                Si[o] += cr*Ti + ci*Tr;
            }
        }
    }

    // width-8 shuffle reduction (the 8 mode-groups are consecutive lanes)
    #pragma unroll
    for (int off = 4; off >= 1; off >>= 1) {
        #pragma unroll
        for (int i = 0; i < NCH*NK2; ++i) {
            Sr[i] += __shfl_down(Sr[i], off, 8);
            Si[i] += __shfl_down(Si[i], off, 8);
        }
    }

    if (g == 0) {
        const float invN = 1.0f / (float)NVOX;
        #pragma unroll
        for (int ch = 0; ch < NCH; ++ch) {
            #pragma unroll
            for (int k2 = 0; k2 < NK2; ++k2) {
                int o = ch*NK2 + k2;
                float sc = (k2 == 0) ? invN : 2.0f*invN;
                S[(o*2 + 0)*8192 + zy] = Sr[o] * sc;
                S[(o*2 + 1)*8192 + zy] = Si[o] * sc;
            }
        }
    }
}

// bc-split: one block per (zy, bc). 8 gathers/thread (vs 96) — full MLP at
// low VGPR; consecutive blocks = 12 bc of the SAME zy, so the concurrent
// fr footprint per XCD drops from ~9 MB (L2-thrash, the residual 2x
// overfetch) to <1 MB. XCD swizzle keeps contiguous zy slabs per XCD.
__global__ __launch_bounds__(256) void deform_sample(
    const float* __restrict__ fr, const float* __restrict__ S,
    float* __restrict__ out)
{
    int i = blockIdx.x;                 // 98304 blocks
    int xcd = i & 7;
    int j = i >> 3;                     // 0..12287
    int zyl = j / NBC;                  // 0..1023
    int bc  = j - zyl * NBC;            // 0..11
    int zy  = (xcd << 10) + zyl;
    int z = zy >> 8, y = zy & 255;
    int x = threadIdx.x;

    // block-uniform S loads (k2=0 imag is mathematically zero -> skip)
    float s0r[NCH], skr[NCH][KMAX], ski[NCH][KMAX];
    #pragma unroll
    for (int ch = 0; ch < NCH; ++ch) {
        s0r[ch] = S[((ch*NK2 + 0)*2 + 0)*8192 + zy];
        #pragma unroll
        for (int k = 1; k <= KMAX; ++k) {
            skr[ch][k-1] = S[((ch*NK2 + k)*2 + 0)*8192 + zy];
            ski[ch][k-1] = S[((ch*NK2 + k)*2 + 1)*8192 + zy];
        }
    }

    // cos/sin(k*theta) for k=1..4, theta = 2*pi*x/256
    float th = (float)x * (6.28318530717958647692f / (float)D2);
    float sb, cb; __sincosf(th, &sb, &cb);
    float ckr[KMAX], cks[KMAX];
    ckr[0] = cb; cks[0] = sb;
    #pragma unroll
    for (int k = 1; k < KMAX; ++k) {
        float nr = ckr[k-1]*cb - cks[k-1]*sb;
        float ni = cks[k-1]*cb + ckr[k-1]*sb;
        ckr[k] = nr; cks[k] = ni;
    }

    float d[NCH];
    #pragma unroll
    for (int ch = 0; ch < NCH; ++ch) {
        float acc = s0r[ch];
        #pragma unroll
        for (int k = 0; k < KMAX; ++k)
            acc += skr[ch][k]*ckr[k] - ski[ch][k]*cks[k];
        d[ch] = acc;
    }

    // coordinates collapse to: f = clip(coord - disp, 0, dim-1)
    float fz = fminf(fmaxf((float)z - d[0], 0.0f), (float)(D0-1));
    float fy = fminf(fmaxf((float)y - d[1], 0.0f), (float)(D1-1));
    float fx = fminf(fmaxf((float)x - d[2], 0.0f), (float)(D2-1));

    float z0f = floorf(fz), y0f = floorf(fy), x0f = floorf(fx);
    int z0 = (int)z0f, y0 = (int)y0f, x0 = (int)x0f;
    int z1 = min(z0 + 1, D0-1), y1 = min(y0 + 1, D1-1), x1 = min(x0 + 1, D2-1);
    float wz = fz - z0f, wy = fy - y0f, wx = fx - x0f;
    float wz0 = 1.0f - wz, wy0 = 1.0f - wy, wx0 = 1.0f - wx;

    const float* __restrict__ v = fr + ((size_t)bc << 21);
    int o00 = (z0 << 16) + (y0 << 8);
    int o01 = (z0 << 16) + (y1 << 8);
    int o10 = (z1 << 16) + (y0 << 8);
    int o11 = (z1 << 16) + (y1 << 8);

    float v000 = v[o00 + x0], v001 = v[o00 + x1];
    float v010 = v[o01 + x0], v011 = v[o01 + x1];
    float v100 = v[o10 + x0], v101 = v[o10 + x1];
    float v110 = v[o11 + x0], v111 = v[o11 + x1];

    float c00 = v000*wx0 + v001*wx;
    float c01 = v010*wx0 + v011*wx;
    float c10 = v100*wx0 + v101*wx;
    float c11 = v110*wx0 + v111*wx;
    float c0 = c00*wy0 + c01*wy;
    float c1 = c10*wy0 + c11*wy;

    // streaming store: don't let 98 MB of output evict fr rows from L2
    __builtin_nontemporal_store(c0*wz0 + c1*wz,
        &out[((size_t)bc << 21) + (zy << 8) + x]);
}

extern "C" void kernel_launch(void* const* d_in, const int* in_sizes, int n_in,
                              void* d_out, int out_size, void* d_ws, size_t ws_size,
                              hipStream_t stream) {
    const float* fr       = (const float*)d_in[0];
    const float* seeds    = (const float*)d_in[1];
    const float* Pk       = (const float*)d_in[2];
    const float* defscale = (const float*)d_in[3];
    // d_in[4] = grid (values are exactly meshgrid(arange) -> recomputed in-kernel)
    const int*   feed_idx = (const int*)d_in[5];
    int fdim = in_sizes[2];

    float* S = (float*)d_ws;   // 245760 floats (~0.96 MB)

    build_S<<<256, 256, 0, stream>>>(seeds, Pk, defscale, feed_idx, fdim, S);
    deform_sample<<<8192*NBC, 256, 0, stream>>>(fr, S, (float*)d_out);
}

// Round 4
// 311.508 us; speedup vs baseline: 1.1766x; 1.0427x over previous
//
#include <hip/hip_runtime.h>
#include <math.h>

// Problem constants
#define D0 32
#define D1 256
#define D2 256
#define HS2 129            // rfft half-spectrum last dim
#define NVOX (D0*D1*D2)    // 2097152
#define KMAX 4
#define NK 9               // k in [-4,4]
#define NK2 5              // k2 in [0,4]
#define NCH 3
#define BATCH 4
#define FCH 3
#define NBC (BATCH*FCH)    // 12
// C layout: [ch][i0][i1][i2][2]  (i0=k0+4, i1=k1+4, i2=k2)
#define C_FLOATS (NCH*NK*NK*NK2*2)   // 2430
// S layout: [(ch*5+k2)*2 + reim][8192]

// 256 blocks x 256 threads: build dense C cube in LDS (scatter, ~fdim loads),
// then 32 zy rows/block, 81-mode sum split 8 ways across consecutive lanes,
// width-8 shuffle reduction.
__global__ __launch_bounds__(256) void build_S(
    const float* __restrict__ seeds, const float* __restrict__ Pk,
    const float* __restrict__ defscale, const int* __restrict__ feed_idx,
    int fdim, float* __restrict__ S)
{
    __shared__ float C[C_FLOATS];
    __shared__ int fed[NK*NK];
    int t = threadIdx.x;
    for (int i = t; i < C_FLOATS; i += 256) C[i] = 0.0f;
    if (t < NK*NK) fed[t] = 0;
    __syncthreads();
    float ds0 = defscale[0], ds1 = defscale[1], ds2 = defscale[2];
    const int STR_RI = D0 * D1 * HS2;   // 1056768
    const int STR_A  = D1 * HS2;        // 33024
    for (int j = t; j < fdim; j += 256) {
        int idx = feed_idx[j];
        int ri = idx / STR_RI; int r = idx - ri * STR_RI;
        int a  = r / STR_A;    r -= a * STR_A;
        int b  = r / HS2;      int c = r - b * HS2;
        int k0 = (a < D0/2) ? a : a - D0;
        int k1 = (b < D1/2) ? b : b - D1;
        if (k0 < -KMAX || k0 > KMAX || k1 < -KMAX || k1 > KMAX || c > KMAX) continue;
        int i0 = k0 + KMAX, i1 = k1 + KMAX;
        float pk = Pk[j];
        int base = ((i0*NK + i1)*NK2 + c)*2 + ri;
        C[base]                 = seeds[0*fdim + j] * pk * ds0;
        C[base + 1*NK*NK*NK2*2] = seeds[1*fdim + j] * pk * ds1;
        C[base + 2*NK*NK*NK2*2] = seeds[2*fdim + j] * pk * ds2;
        if (c == 0) fed[i0*NK + i1] = 1;
    }
    __syncthreads();
    // hermitian completion on the k2=0 plane: unfed <- conj(mirror)
    if (t < NK*NK && !fed[t]) {
        int i0 = t / NK, i1 = t - i0*NK;
        int m0 = (NK-1) - i0, m1 = (NK-1) - i1;
        for (int ch = 0; ch < NCH; ++ch) {
            int dst = ((ch*NK*NK + i0*NK + i1)*NK2 + 0)*2;
            int src = ((ch*NK*NK + m0*NK + m1)*NK2 + 0)*2;
            C[dst]   = C[src];
            C[dst+1] = -C[src+1];
        }
    }
    __syncthreads();

    int zyl = t >> 3;           // 0..31  (consecutive lanes share zyl)
    int g   = t & 7;            // mode group 0..7
    int zy = blockIdx.x * 32 + zyl;
    int z = zy >> 8, y = zy & 255;

    float w0r[NK], w0i[NK], w1r[NK], w1i[NK];
    {
        float th = (float)z * (6.28318530717958647692f / (float)D0);
        float sb, cb; __sincosf(th, &sb, &cb);
        w0r[KMAX] = 1.0f; w0i[KMAX] = 0.0f;
        float pr = 1.0f, pi = 0.0f;
        #pragma unroll
        for (int k = 1; k <= KMAX; ++k) {
            float nr = pr*cb - pi*sb, ni = pr*sb + pi*cb;
            pr = nr; pi = ni;
            w0r[KMAX+k] = pr; w0i[KMAX+k] = pi;
            w0r[KMAX-k] = pr; w0i[KMAX-k] = -pi;
        }
    }
    {
        float th = (float)y * (6.28318530717958647692f / (float)D1);
        float sb, cb; __sincosf(th, &sb, &cb);
        w1r[KMAX] = 1.0f; w1i[KMAX] = 0.0f;
        float pr = 1.0f, pi = 0.0f;
        #pragma unroll
        for (int k = 1; k <= KMAX; ++k) {
            float nr = pr*cb - pi*sb, ni = pr*sb + pi*cb;
            pr = nr; pi = ni;
            w1r[KMAX+k] = pr; w1i[KMAX+k] = pi;
            w1r[KMAX-k] = pr; w1i[KMAX-k] = -pi;
        }
    }

    float Sr[NCH*NK2], Si[NCH*NK2];
    #pragma unroll
    for (int i = 0; i < NCH*NK2; ++i) { Sr[i] = 0.0f; Si[i] = 0.0f; }

    for (int m = g; m < NK*NK; m += 8) {
        int i0 = m / NK, i1 = m - i0*NK;
        float Tr = w0r[i0]*w1r[i1] - w0i[i0]*w1i[i1];
        float Ti = w0r[i0]*w1i[i1] + w0i[i0]*w1r[i1];
        const float* Cp = C + m*NK2*2;
        #pragma unroll
        for (int ch = 0; ch < NCH; ++ch) {
            #pragma unroll
            for (int k2 = 0; k2 < NK2; ++k2) {
                float cr = Cp[ch*(NK*NK*NK2*2) + k2*2];
                float ci = Cp[ch*(NK*NK*NK2*2) + k2*2 + 1];
                int o = ch*NK2 + k2;
                Sr[o] += cr*Tr - ci*Ti;
                Si[o] += cr*Ti + ci*Tr;
            }
        }
    }

    #pragma unroll
    for (int off = 4; off >= 1; off >>= 1) {
        #pragma unroll
        for (int i = 0; i < NCH*NK2; ++i) {
            Sr[i] += __shfl_down(Sr[i], off, 8);
            Si[i] += __shfl_down(Si[i], off, 8);
        }
    }

    if (g == 0) {
        const float invN = 1.0f / (float)NVOX;
        #pragma unroll
        for (int ch = 0; ch < NCH; ++ch) {
            #pragma unroll
            for (int k2 = 0; k2 < NK2; ++k2) {
                int o = ch*NK2 + k2;
                float sc = (k2 == 0) ? invN : 2.0f*invN;
                S[(o*2 + 0)*8192 + zy] = Sr[o] * sc;
                S[(o*2 + 1)*8192 + zy] = Si[o] * sc;
            }
        }
    }
}

// One block per (zy, channel-group-of-3). The 3 output channels of one batch
// share IDENTICAL displacement (disp depends only on the deform channel), so
// disp is computed once per block and applied to 3 gathers+stores.
// XCD mapping: 4 groups x 2 z-halves = 8 units == 8 XCDs (block i -> XCD i&7).
// Per-XCD concurrent fr footprint: 3 bc x ~2.5 z-planes x 256 KB ~= 2 MB < 4 MB
// L2 -> z-plane reuse now survives (was 6 MB with all 12 bc per XCD, the
// source of the residual 2x overfetch: FETCH 200 MB vs 100 MB ideal).
__global__ __launch_bounds__(256) void deform_sample(
    const float* __restrict__ fr, const float* __restrict__ S,
    float* __restrict__ out)
{
    int i = blockIdx.x;                 // 32768 blocks
    int u = i & 7;                      // XCD id = unit id
    int b  = u >> 1;                    // batch (channel group) 0..3
    int zh = u & 1;                     // z-half 0..1
    int j = i >> 3;                     // 0..4095 within unit; y sweeps fastest
    int z = (zh << 4) + (j >> 8);
    int y = j & 255;
    int zy = (z << 8) + y;
    int x = threadIdx.x;

    // block-uniform S loads (k2=0 imag is mathematically zero -> skip)
    float s0r[NCH], skr[NCH][KMAX], ski[NCH][KMAX];
    #pragma unroll
    for (int ch = 0; ch < NCH; ++ch) {
        s0r[ch] = S[((ch*NK2 + 0)*2 + 0)*8192 + zy];
        #pragma unroll
        for (int k = 1; k <= KMAX; ++k) {
            skr[ch][k-1] = S[((ch*NK2 + k)*2 + 0)*8192 + zy];
            ski[ch][k-1] = S[((ch*NK2 + k)*2 + 1)*8192 + zy];
        }
    }

    // cos/sin(k*theta) for k=1..4, theta = 2*pi*x/256
    float th = (float)x * (6.28318530717958647692f / (float)D2);
    float sb, cb; __sincosf(th, &sb, &cb);
    float ckr[KMAX], cks[KMAX];
    ckr[0] = cb; cks[0] = sb;
    #pragma unroll
    for (int k = 1; k < KMAX; ++k) {
        float nr = ckr[k-1]*cb - cks[k-1]*sb;
        float ni = cks[k-1]*cb + ckr[k-1]*sb;
        ckr[k] = nr; cks[k] = ni;
    }

    float d[NCH];
    #pragma unroll
    for (int ch = 0; ch < NCH; ++ch) {
        float acc = s0r[ch];
        #pragma unroll
        for (int k = 0; k < KMAX; ++k)
            acc += skr[ch][k]*ckr[k] - ski[ch][k]*cks[k];
        d[ch] = acc;
    }

    // coordinates collapse to: f = clip(coord - disp, 0, dim-1)
    float fz = fminf(fmaxf((float)z - d[0], 0.0f), (float)(D0-1));
    float fy = fminf(fmaxf((float)y - d[1], 0.0f), (float)(D1-1));
    float fx = fminf(fmaxf((float)x - d[2], 0.0f), (float)(D2-1));

    float z0f = floorf(fz), y0f = floorf(fy), x0f = floorf(fx);
    int z0 = (int)z0f, y0 = (int)y0f, x0 = (int)x0f;
    int z1 = min(z0 + 1, D0-1), y1 = min(y0 + 1, D1-1), x1 = min(x0 + 1, D2-1);
    float wz = fz - z0f, wy = fy - y0f, wx = fx - x0f;
    float wz0 = 1.0f - wz, wy0 = 1.0f - wy, wx0 = 1.0f - wx;

    int o00 = (z0 << 16) + (y0 << 8);
    int o01 = (z0 << 16) + (y1 << 8);
    int o10 = (z1 << 16) + (y0 << 8);
    int o11 = (z1 << 16) + (y1 << 8);

    // 3 channels of batch b: bc = b*3 + {0,1,2}; identical disp/weights.
    const float* __restrict__ v0p = fr + ((size_t)(b*3 + 0) << 21);
    const float* __restrict__ v1p = fr + ((size_t)(b*3 + 1) << 21);
    const float* __restrict__ v2p = fr + ((size_t)(b*3 + 2) << 21);
    size_t ob = ((size_t)(b*3) << 21) + (zy << 8) + x;

    #pragma unroll
    for (int c = 0; c < 3; ++c) {
        const float* __restrict__ v = (c == 0) ? v0p : (c == 1) ? v1p : v2p;
        float c00 = v[o00 + x0]*wx0 + v[o00 + x1]*wx;
        float c01 = v[o01 + x0]*wx0 + v[o01 + x1]*wx;
        float c10 = v[o10 + x0]*wx0 + v[o10 + x1]*wx;
        float c11 = v[o11 + x0]*wx0 + v[o11 + x1]*wx;
        float cc0 = c00*wy0 + c01*wy;
        float cc1 = c10*wy0 + c11*wy;
        // streaming store: don't let output evict fr rows from L2
        __builtin_nontemporal_store(cc0*wz0 + cc1*wz, &out[ob + ((size_t)c << 21)]);
    }
}

extern "C" void kernel_launch(void* const* d_in, const int* in_sizes, int n_in,
                              void* d_out, int out_size, void* d_ws, size_t ws_size,
                              hipStream_t stream) {
    const float* fr       = (const float*)d_in[0];
    const float* seeds    = (const float*)d_in[1];
    const float* Pk       = (const float*)d_in[2];
    const float* defscale = (const float*)d_in[3];
    // d_in[4] = grid (values are exactly meshgrid(arange) -> recomputed in-kernel)
    const int*   feed_idx = (const int*)d_in[5];
    int fdim = in_sizes[2];

    float* S = (float*)d_ws;   // 245760 floats (~0.96 MB)

    build_S<<<256, 256, 0, stream>>>(seeds, Pk, defscale, feed_idx, fdim, S);
    deform_sample<<<8192*4, 256, 0, stream>>>(fr, S, (float*)d_out);
}

// Round 5
// 281.352 us; speedup vs baseline: 1.3027x; 1.1072x over previous
//
#include <hip/hip_runtime.h>
#include <math.h>

// Problem constants
#define D0 32
#define D1 256
#define D2 256
#define HS2 129            // rfft half-spectrum last dim
#define NVOX (D0*D1*D2)    // 2097152
#define KMAX 4
#define NK 9               // k in [-4,4]
#define NK2 5              // k2 in [0,4]
#define NCH 3
#define BATCH 4
#define FCH 3
#define NBC (BATCH*FCH)    // 12
// C layout: [ch][i0][i1][i2][2]  (i0=k0+4, i1=k1+4, i2=k2)
#define C_FLOATS (NCH*NK*NK*NK2*2)   // 2430
// S layout: [zy][32] floats; slot = ch*10 + k2*2 + reim  (30 used, pad to 32)
// -> all 30 per-row coefficients are wave-uniform contiguous: scalar loads.

typedef float v2f __attribute__((ext_vector_type(2)));

// 256 blocks x 256 threads: build dense C cube in LDS (scatter, ~fdim loads),
// then 32 zy rows/block, 81-mode sum split 8 ways across consecutive lanes,
// width-8 shuffle reduction.
__global__ __launch_bounds__(256) void build_S(
    const float* __restrict__ seeds, const float* __restrict__ Pk,
    const float* __restrict__ defscale, const int* __restrict__ feed_idx,
    int fdim, float* __restrict__ S)
{
    __shared__ float C[C_FLOATS];
    __shared__ int fed[NK*NK];
    int t = threadIdx.x;
    for (int i = t; i < C_FLOATS; i += 256) C[i] = 0.0f;
    if (t < NK*NK) fed[t] = 0;
    __syncthreads();
    float ds0 = defscale[0], ds1 = defscale[1], ds2 = defscale[2];
    const int STR_RI = D0 * D1 * HS2;   // 1056768
    const int STR_A  = D1 * HS2;        // 33024
    for (int j = t; j < fdim; j += 256) {
        int idx = feed_idx[j];
        int ri = idx / STR_RI; int r = idx - ri * STR_RI;
        int a  = r / STR_A;    r -= a * STR_A;
        int b  = r / HS2;      int c = r - b * HS2;
        int k0 = (a < D0/2) ? a : a - D0;
        int k1 = (b < D1/2) ? b : b - D1;
        if (k0 < -KMAX || k0 > KMAX || k1 < -KMAX || k1 > KMAX || c > KMAX) continue;
        int i0 = k0 + KMAX, i1 = k1 + KMAX;
        float pk = Pk[j];
        int base = ((i0*NK + i1)*NK2 + c)*2 + ri;
        C[base]                 = seeds[0*fdim + j] * pk * ds0;
        C[base + 1*NK*NK*NK2*2] = seeds[1*fdim + j] * pk * ds1;
        C[base + 2*NK*NK*NK2*2] = seeds[2*fdim + j] * pk * ds2;
        if (c == 0) fed[i0*NK + i1] = 1;
    }
    __syncthreads();
    // hermitian completion on the k2=0 plane: unfed <- conj(mirror)
    if (t < NK*NK && !fed[t]) {
        int i0 = t / NK, i1 = t - i0*NK;
        int m0 = (NK-1) - i0, m1 = (NK-1) - i1;
        for (int ch = 0; ch < NCH; ++ch) {
            int dst = ((ch*NK*NK + i0*NK + i1)*NK2 + 0)*2;
            int src = ((ch*NK*NK + m0*NK + m1)*NK2 + 0)*2;
            C[dst]   = C[src];
            C[dst+1] = -C[src+1];
        }
    }
    __syncthreads();

    int zyl = t >> 3;           // 0..31  (consecutive lanes share zyl)
    int g   = t & 7;            // mode group 0..7
    int zy = blockIdx.x * 32 + zyl;
    int z = zy >> 8, y = zy & 255;

    float w0r[NK], w0i[NK], w1r[NK], w1i[NK];
    {
        float th = (float)z * (6.28318530717958647692f / (float)D0);
        float sb, cb; __sincosf(th, &sb, &cb);
        w0r[KMAX] = 1.0f; w0i[KMAX] = 0.0f;
        float pr = 1.0f, pi = 0.0f;
        #pragma unroll
        for (int k = 1; k <= KMAX; ++k) {
            float nr = pr*cb - pi*sb, ni = pr*sb + pi*cb;
            pr = nr; pi = ni;
            w0r[KMAX+k] = pr; w0i[KMAX+k] = pi;
            w0r[KMAX-k] = pr; w0i[KMAX-k] = -pi;
        }
    }
    {
        float th = (float)y * (6.28318530717958647692f / (float)D1);
        float sb, cb; __sincosf(th, &sb, &cb);
        w1r[KMAX] = 1.0f; w1i[KMAX] = 0.0f;
        float pr = 1.0f, pi = 0.0f;
        #pragma unroll
        for (int k = 1; k <= KMAX; ++k) {
            float nr = pr*cb - pi*sb, ni = pr*sb + pi*cb;
            pr = nr; pi = ni;
            w1r[KMAX+k] = pr; w1i[KMAX+k] = pi;
            w1r[KMAX-k] = pr; w1i[KMAX-k] = -pi;
        }
    }

    float Sr[NCH*NK2], Si[NCH*NK2];
    #pragma unroll
    for (int i = 0; i < NCH*NK2; ++i) { Sr[i] = 0.0f; Si[i] = 0.0f; }

    for (int m = g; m < NK*NK; m += 8) {
        int i0 = m / NK, i1 = m - i0*NK;
        float Tr = w0r[i0]*w1r[i1] - w0i[i0]*w1i[i1];
        float Ti = w0r[i0]*w1i[i1] + w0i[i0]*w1r[i1];
        const float* Cp = C + m*NK2*2;
        #pragma unroll
        for (int ch = 0; ch < NCH; ++ch) {
            #pragma unroll
            for (int k2 = 0; k2 < NK2; ++k2) {
                float cr = Cp[ch*(NK*NK*NK2*2) + k2*2];
                float ci = Cp[ch*(NK*NK*NK2*2) + k2*2 + 1];
                int o = ch*NK2 + k2;
                Sr[o] += cr*Tr - ci*Ti;
                Si[o] += cr*Ti + ci*Tr;
            }
        }
    }

    #pragma unroll
    for (int off = 4; off >= 1; off >>= 1) {
        #pragma unroll
        for (int i = 0; i < NCH*NK2; ++i) {
            Sr[i] += __shfl_down(Sr[i], off, 8);
            Si[i] += __shfl_down(Si[i], off, 8);
        }
    }

    if (g == 0) {
        const float invN = 1.0f / (float)NVOX;
        float* Sp = S + (size_t)zy * 32;
        #pragma unroll
        for (int ch = 0; ch < NCH; ++ch) {
            #pragma unroll
            for (int k2 = 0; k2 < NK2; ++k2) {
                int o = ch*NK2 + k2;
                float sc = (k2 == 0) ? invN : 2.0f*invN;
                Sp[ch*10 + k2*2 + 0] = Sr[o] * sc;
                Sp[ch*10 + k2*2 + 1] = Si[o] * sc;
            }
        }
    }
}

// One block per (zy, batch). The 3 output channels of one batch share ONE
// displacement. XCD mapping: 4 batches x 2 z-halves = 8 units == 8 XCDs.
// Gather loads merged: x0/x1 pair touches the SAME cache lines -> one float2
// load per (row,channel) = 12 gather instrs/thread instead of 24. This halves
// the per-CU TA/L1 line-processing work, which (not HBM BW: 73 MB fetch @
// 13% peak, not VALU: 26%) is the invariant bottleneck across rounds 2-4.
// Edge x0==255: load at min(x0,254), select (.y,.y) branchlessly.
// S is [zy][32]: wave-uniform -> compiler emits scalar s_load (kills ~80
// VALU/wave of vector loads + addressing vs the strided layout).
__global__ __launch_bounds__(256) void deform_sample(
    const float* __restrict__ fr, const float* __restrict__ S,
    float* __restrict__ out)
{
    int i = blockIdx.x;                 // 32768 blocks
    int u = i & 7;                      // XCD id = unit id
    int b  = u >> 1;                    // batch (channel group) 0..3
    int zh = u & 1;                     // z-half 0..1
    int j = i >> 3;                     // 0..4095 within unit; y sweeps fastest
    int z = (zh << 4) + (j >> 8);
    int y = j & 255;
    int zy = (z << 8) + y;
    int x = threadIdx.x;

    // 30 wave-uniform coefficients -> scalar loads
    const float* __restrict__ Sp = S + (size_t)zy * 32;
    float s[30];
    #pragma unroll
    for (int q = 0; q < 30; ++q) s[q] = Sp[q];

    // cos/sin(k*theta) for k=1..4, theta = 2*pi*x/256
    float th = (float)x * (6.28318530717958647692f / (float)D2);
    float sb, cb; __sincosf(th, &sb, &cb);
    float ckr[KMAX], cks[KMAX];
    ckr[0] = cb; cks[0] = sb;
    #pragma unroll
    for (int k = 1; k < KMAX; ++k) {
        float nr = ckr[k-1]*cb - cks[k-1]*sb;
        float ni = cks[k-1]*cb + ckr[k-1]*sb;
        ckr[k] = nr; cks[k] = ni;
    }

    float d[NCH];
    #pragma unroll
    for (int ch = 0; ch < NCH; ++ch) {
        float acc = s[ch*10 + 0];
        #pragma unroll
        for (int k = 1; k <= KMAX; ++k)
            acc += s[ch*10 + k*2]*ckr[k-1] - s[ch*10 + k*2 + 1]*cks[k-1];
        d[ch] = acc;
    }

    // coordinates collapse to: f = clip(coord - disp, 0, dim-1)
    float fz = fminf(fmaxf((float)z - d[0], 0.0f), (float)(D0-1));
    float fy = fminf(fmaxf((float)y - d[1], 0.0f), (float)(D1-1));
    float fx = fminf(fmaxf((float)x - d[2], 0.0f), (float)(D2-1));

    float z0f = floorf(fz), y0f = floorf(fy), x0f = floorf(fx);
    int z0 = (int)z0f, y0 = (int)y0f, x0 = (int)x0f;
    int z1 = min(z0 + 1, D0-1), y1 = min(y0 + 1, D1-1);
    float wz = fz - z0f, wy = fy - y0f, wx = fx - x0f;

    int xm = min(x0, D2-2);             // float2 stays in-row
    bool hi = (x0 > xm);                // x0 == 255 -> use (.y,.y)

    int o00 = (z0 << 16) + (y0 << 8) + xm;
    int o01 = (z0 << 16) + (y1 << 8) + xm;
    int o10 = (z1 << 16) + (y0 << 8) + xm;
    int o11 = (z1 << 16) + (y1 << 8) + xm;

    // issue all 12 float2 gathers before consuming (MLP)
    v2f P[FCH][4];
    #pragma unroll
    for (int c = 0; c < FCH; ++c) {
        const float* __restrict__ v = fr + ((size_t)(b*FCH + c) << 21);
        P[c][0] = *(const v2f*)(v + o00);
        P[c][1] = *(const v2f*)(v + o01);
        P[c][2] = *(const v2f*)(v + o10);
        P[c][3] = *(const v2f*)(v + o11);
    }

    size_t ob = ((size_t)(b*FCH) << 21) + ((size_t)zy << 8) + x;
    #pragma unroll
    for (int c = 0; c < FCH; ++c) {
        float a00 = hi ? P[c][0].y : P[c][0].x;
        float a01 = hi ? P[c][1].y : P[c][1].x;
        float a10 = hi ? P[c][2].y : P[c][2].x;
        float a11 = hi ? P[c][3].y : P[c][3].x;
        float c00 = a00 + wx * (P[c][0].y - a00);
        float c01 = a01 + wx * (P[c][1].y - a01);
        float c10 = a10 + wx * (P[c][2].y - a10);
        float c11 = a11 + wx * (P[c][3].y - a11);
        float c0 = c00 + wy * (c01 - c00);
        float c1 = c10 + wy * (c11 - c10);
        // streaming store: don't let output evict fr rows from L2
        __builtin_nontemporal_store(c0 + wz * (c1 - c0),
                                    &out[ob + ((size_t)c << 21)]);
    }
}

extern "C" void kernel_launch(void* const* d_in, const int* in_sizes, int n_in,
                              void* d_out, int out_size, void* d_ws, size_t ws_size,
                              hipStream_t stream) {
    const float* fr       = (const float*)d_in[0];
    const float* seeds    = (const float*)d_in[1];
    const float* Pk       = (const float*)d_in[2];
    const float* defscale = (const float*)d_in[3];
    // d_in[4] = grid (values are exactly meshgrid(arange) -> recomputed in-kernel)
    const int*   feed_idx = (const int*)d_in[5];
    int fdim = in_sizes[2];

    float* S = (float*)d_ws;   // 8192 * 32 floats = 1 MB

    build_S<<<256, 256, 0, stream>>>(seeds, Pk, defscale, feed_idx, fdim, S);
    deform_sample<<<8192*4, 256, 0, stream>>>(fr, S, (float*)d_out);
}